// Round 13
// baseline (80.554 us; speedup 1.0000x reference)
//
#include <hip/hip_runtime.h>

// PSROI pooling: fsam (N=8, C=245, H=80, W=80) f32, box (R=8192, 5) f32
// out (R, 245) f32. out[r, c] = mean over fsam[b, c, hs:he, ws:we].
//
// ARITHMETIC (frozen since R10, DO NOT TOUCH): bin = roi * fl32(1/7)
// (reciprocal multiply, 0x3E124925) and edges = SEPARATELY-rounded
// g*bin + off (asm barriers). Matches ref (absmax <= 0.016 << 0.0725).
//
// R13: FUSED per-plane kernel. R12 round-tripped a 51MB SAT through
// memory and the pool kernel's 4 gathers/thread touched ~64 L2 lines per
// wave (~512MB L2 traffic). Now: block = (channel c, image b) builds the
// padded 81x81 SAT for its plane IN LDS (26.2KB) and pools image-b ROIs
// directly from LDS. fsam read exactly once (L3-resident on replays), no
// SAT traffic, gathers are LDS. A tiny atomic kernel buckets ROIs by
// image first (order nondeterministic; output per-ROI independent ->
// deterministic). b = blockIdx.x&7 is the XCD swizzle: one image per XCD,
// so each out[r,:] row assembles within one XCD's L2.

#define N_ 8
#define C_ 245
#define H_ 80
#define W_ 80
#define R_ 8192
#define P_ 7
#define SATW 81

// XLA-style separately-rounded a*b + c in f32; barriers forbid contraction.
__device__ __forceinline__ float sep_ma(float a, float b, float c) {
    float p = a * b;                 // v_mul_f32, IEEE RN
    asm volatile("" : "+v"(p));      // contraction barrier
    float s = p + c;                 // v_add_f32, IEEE RN
    asm volatile("" : "+v"(s));
    return s;
}

// ---------------- kernel 1: bucket ROIs by image ----------------
__global__ __launch_bounds__(256) void bucket_kernel(
    const float* __restrict__ box, int* __restrict__ cnt,
    int* __restrict__ buckets)
{
    int r = blockIdx.x * 256 + threadIdx.x;
    if (r >= R_) return;
    int b = (int)box[(size_t)r * 5];
    int slot = atomicAdd(&cnt[b], 1);        // device-scope, cross-XCD safe
    buckets[b * R_ + slot] = r;
}

// ---------------- kernel 2: fused SAT-in-LDS + pool ----------------
__global__ __launch_bounds__(256) void fused_kernel(
    const float* __restrict__ fsam,
    const float* __restrict__ box,
    const int* __restrict__ cnt,
    const int* __restrict__ buckets,
    float* __restrict__ out)
{
    __shared__ float S[SATW * SATW];         // 26244 B
    int id  = blockIdx.x;                    // 0..1959
    int b   = id & 7;                        // image  (XCD swizzle)
    int c   = id >> 3;                       // channel 0..244
    int tid = threadIdx.x;

    const float* plane = fsam + ((size_t)b * C_ + c) * (H_ * W_);

    // load plane into padded position; row 0 / col 0 zeroed
    for (int i = tid; i < SATW * SATW; i += 256) {
        int row = i / SATW, col = i - row * SATW;
        S[i] = (row && col) ? plane[(row - 1) * W_ + (col - 1)] : 0.0f;
    }
    __syncthreads();

    // horizontal cumsum, rows 1..80 (one thread per row; stride-81 across
    // lanes -> conflict-free since gcd(81,32)=1)
    if (tid >= 1 && tid < SATW) {
        float run = 0.0f; int base = tid * SATW;
        for (int j = 1; j < SATW; ++j) { run += S[base + j]; S[base + j] = run; }
    }
    __syncthreads();

    // vertical cumsum, cols 1..80 (one thread per col; consecutive lanes ->
    // consecutive banks, conflict-free)
    if (tid >= 1 && tid < SATW) {
        float run = 0.0f;
        for (int i = 1; i < SATW; ++i) {
            run += S[i * SATW + tid]; S[i * SATW + tid] = run;
        }
    }
    __syncthreads();

    // pool this image's ROIs from the LDS SAT
    int ph = (c / P_) % P_;                  // block-uniform
    int pw = c % P_;
    int n  = cnt[b];
    const int* lst = buckets + b * R_;

    for (int i = tid; i < n; i += 256) {
        int r = lst[i];
        const float* bx = box + (size_t)r * 5;

        // ---- R10-frozen edge arithmetic ----
        float x1 = rintf(bx[1]);
        float y1 = rintf(bx[2]);
        float x2 = rintf(bx[3] + 1.0f);
        float y2 = rintf(bx[4] + 1.0f);

        float roi_w = fmaxf(x2 - x1, 0.1f);
        float roi_h = fmaxf(y2 - y1, 0.1f);

        const float RCP7 = __uint_as_float(0x3E124925u);  // fl32(1/7)
        float bin_w = roi_w * RCP7;
        float bin_h = roi_h * RCP7;
        asm volatile("" : "+v"(bin_w), "+v"(bin_h));

        float hs_f = floorf(sep_ma((float)ph,       bin_h, y1));
        float he_f = ceilf (sep_ma((float)(ph + 1), bin_h, y1));
        float ws_f = floorf(sep_ma((float)pw,       bin_w, x1));
        float we_f = ceilf (sep_ma((float)(pw + 1), bin_w, x1));

        int hs = (int)fminf(fmaxf(hs_f, 0.0f), 80.0f);
        int he = (int)fminf(fmaxf(he_f, 0.0f), 80.0f);
        int ws = (int)fminf(fmaxf(ws_f, 0.0f), 80.0f);
        int we = (int)fminf(fmaxf(we_f, 0.0f), 80.0f);

        // bin sum from LDS SAT, reference op order
        float s11 = S[he * SATW + we];
        float s01 = S[hs * SATW + we];
        float s10 = S[he * SATW + ws];
        float s00 = S[hs * SATW + ws];
        float bin_sum = ((s11 - s01) - s10) + s00;

        int area = (he - hs) * (we - ws);
        out[(size_t)r * C_ + c] = (area > 0) ? bin_sum / (float)area : 0.0f;
    }
}

// ---------------- fallback: R11 direct-sum kernel (ws too small) -----------
__global__ __launch_bounds__(256) void psroi_direct_kernel(
    const float* __restrict__ fsam,
    const float* __restrict__ box,
    float* __restrict__ out)
{
    int id = blockIdx.x;
    int j  = id & 7;
    int m  = id >> 3;
    int g  = (m < 512) ? j : j + 8;
    int l  = (m < 512) ? m : m - 512;
    int c    = g * 16 + (l >> 5);
    int rblk = l & 31;
    if (c >= C_) return;

    int r = rblk * 256 + (int)threadIdx.x;
    int pw = c % P_;
    int ph = (c / P_) % P_;

    const float* bx = box + (size_t)r * 5;
    int   b  = (int)bx[0];
    float x1 = rintf(bx[1]);
    float y1 = rintf(bx[2]);
    float x2 = rintf(bx[3] + 1.0f);
    float y2 = rintf(bx[4] + 1.0f);

    float roi_w = fmaxf(x2 - x1, 0.1f);
    float roi_h = fmaxf(y2 - y1, 0.1f);

    const float RCP7 = __uint_as_float(0x3E124925u);
    float bin_w = roi_w * RCP7;
    float bin_h = roi_h * RCP7;
    asm volatile("" : "+v"(bin_w), "+v"(bin_h));

    float hs_f = floorf(sep_ma((float)ph,       bin_h, y1));
    float he_f = ceilf (sep_ma((float)(ph + 1), bin_h, y1));
    float ws_f = floorf(sep_ma((float)pw,       bin_w, x1));
    float we_f = ceilf (sep_ma((float)(pw + 1), bin_w, x1));

    int hs = (int)fminf(fmaxf(hs_f, 0.0f), 80.0f);
    int he = (int)fminf(fmaxf(he_f, 0.0f), 80.0f);
    int ws = (int)fminf(fmaxf(ws_f, 0.0f), 80.0f);
    int we = (int)fminf(fmaxf(we_f, 0.0f), 80.0f);

    const float* plane = fsam + ((size_t)b * C_ + c) * (H_ * W_);
    float s = 0.0f;
    for (int y = hs; y < he; ++y) {
        const float* row = plane + y * W_;
        for (int x = ws; x < we; ++x) s += row[x];
    }
    int area = (he - hs) * (we - ws);
    out[(size_t)r * C_ + c] = (area > 0) ? s / (float)area : 0.0f;
}

extern "C" void kernel_launch(void* const* d_in, const int* in_sizes, int n_in,
                              void* d_out, int out_size, void* d_ws, size_t ws_size,
                              hipStream_t stream) {
    const float* fsam = (const float*)d_in[0];
    const float* box  = (const float*)d_in[1];
    float* out = (float*)d_out;

    // ws layout: [0,32) counters (8 ints, padded), [32, 32+8*8192*4) buckets
    size_t need = 32 + (size_t)N_ * R_ * sizeof(int);   // 262176 B
    if (ws_size >= need) {
        int* cnt     = (int*)d_ws;
        int* buckets = (int*)((char*)d_ws + 32);
        hipMemsetAsync(cnt, 0, 32, stream);             // zero counters
        bucket_kernel<<<(R_ + 255) / 256, 256, 0, stream>>>(box, cnt, buckets);
        fused_kernel<<<N_ * C_, 256, 0, stream>>>(fsam, box, cnt, buckets, out);
    } else {
        psroi_direct_kernel<<<8192, 256, 0, stream>>>(fsam, box, out);
    }
}

// Round 14
// 45.086 us; speedup vs baseline: 1.7867x; 1.7867x over previous
//
#include <hip/hip_runtime.h>

// PSROI pooling: fsam (N=8, C=245, H=80, W=80) f32, box (R=8192, 5) f32
// out (R, 245) f32. out[r, c] = mean over fsam[b, c, hs:he, ws:we].
//
// ARITHMETIC (frozen since R10, DO NOT TOUCH): bin = roi * fl32(1/7)
// (reciprocal multiply, 0x3E124925) and edges = SEPARATELY-rounded
// g*bin + off (asm barriers). Matches ref (absmax <= 0.016 << 0.0725).
//
// R14: fused per-plane SAT-in-LDS (R13) with the serial bottlenecks fixed:
//  - bucket kernel is deterministic (count -> LDS scan -> ordered write):
//    no atomics, no memset dispatch; buckets ascending in r.
//  - SAT scans chunked: 80 rows/cols x 2 halves of 40 (160 threads), local
//    serial scan + __shfl_xor chunk-total swap + independent offset pass.
//    Dependent LDS-RMW chain halves; offset pass fully pipelined.
//  - plane loaded as float4 (1600 x 16B, coalesced), unrolled scans.
// Chunk-1 reorder vs ref cumsum adds <= ~4e-4 (headroom 18x).

#define N_ 8
#define C_ 245
#define H_ 80
#define W_ 80
#define R_ 8192
#define P_ 7
#define SATW 81

// XLA-style separately-rounded a*b + c in f32; barriers forbid contraction.
__device__ __forceinline__ float sep_ma(float a, float b, float c) {
    float p = a * b;                 // v_mul_f32, IEEE RN
    asm volatile("" : "+v"(p));      // contraction barrier
    float s = p + c;                 // v_add_f32, IEEE RN
    asm volatile("" : "+v"(s));
    return s;
}

// ---- kernel 1: deterministic bucket build (8 blocks, no atomics) ----
__global__ __launch_bounds__(256) void bucket_kernel(
    const float* __restrict__ box, int* __restrict__ cnt,
    int* __restrict__ buckets)
{
    __shared__ int psum[256];
    int b = blockIdx.x;                    // image
    int t = threadIdx.x;
    int r0 = t * 32;                       // contiguous range per thread

    int m = 0;
    for (int k = 0; k < 32; ++k)
        if ((int)box[(size_t)(r0 + k) * 5] == b) ++m;
    psum[t] = m;
    __syncthreads();

    // Hillis-Steele inclusive scan over 256 counts
    for (int off = 1; off < 256; off <<= 1) {
        int v = (t >= off) ? psum[t - off] : 0;
        __syncthreads();
        psum[t] += v;
        __syncthreads();
    }
    int pos = psum[t] - m;                 // exclusive prefix
    for (int k = 0; k < 32; ++k) {
        int r = r0 + k;
        if ((int)box[(size_t)r * 5] == b) buckets[b * R_ + pos++] = r;
    }
    if (t == 255) cnt[b] = psum[255];
}

// ---- kernel 2: fused SAT-in-LDS + pool ----
__global__ __launch_bounds__(256) void fused_kernel(
    const float* __restrict__ fsam,
    const float* __restrict__ box,
    const int* __restrict__ cnt,
    const int* __restrict__ buckets,
    float* __restrict__ out)
{
    __shared__ float S[SATW * SATW];       // 26244 B
    int id  = blockIdx.x;                  // 0..1959
    int b   = id & 7;                      // image (XCD swizzle: XCD = b)
    int c   = id >> 3;                     // channel 0..244
    int tid = threadIdx.x;

    const float* plane = fsam + ((size_t)b * C_ + c) * (H_ * W_);

    // zero pad row 0 and col 0
    if (tid < SATW) S[tid] = 0.0f;                       // row 0
    if (tid >= 81 && tid < 161) S[(tid - 80) * SATW] = 0.0f;  // col 0, rows 1..80

    // coalesced float4 load: 6400 floats = 1600 float4
    for (int i = tid; i < 1600; i += 256) {
        float4 v = ((const float4*)plane)[i];
        int flat = i * 4;
        int row  = (int)((unsigned)flat / 80u);          // magic-mul
        int col  = flat - row * 80;                      // %4==0, no row cross
        float* p = &S[(row + 1) * SATW + col + 1];
        p[0] = v.x; p[1] = v.y; p[2] = v.z; p[3] = v.w;
    }
    __syncthreads();

    // horizontal scan: 160 threads = 80 rows x 2 chunks of 40
    if (tid < 160) {
        int row  = tid >> 1, half = tid & 1;
        int base = (row + 1) * SATW + 1 + half * 40;
        float run = 0.0f;
        #pragma unroll
        for (int j = 0; j < 40; ++j) { run += S[base + j]; S[base + j] = run; }
        float other = __shfl_xor(run, 1);                // partner chunk total
        if (half) {
            #pragma unroll
            for (int j = 0; j < 40; ++j) S[base + j] += other;
        }
    }
    __syncthreads();

    // vertical scan: 160 threads = 80 cols (1..80) x 2 chunks of 40 rows
    if (tid < 160) {
        int col  = (tid >> 1) + 1, half = tid & 1;
        int base = (1 + half * 40) * SATW + col;
        float run = 0.0f;
        #pragma unroll
        for (int j = 0; j < 40; ++j) { run += S[base + j * SATW]; S[base + j * SATW] = run; }
        float other = __shfl_xor(run, 1);
        if (half) {
            #pragma unroll
            for (int j = 0; j < 40; ++j) S[base + j * SATW] += other;
        }
    }
    __syncthreads();

    // pool this image's ROIs from the LDS SAT
    int ph = (c / P_) % P_;                // block-uniform
    int pw = c % P_;
    int n  = cnt[b];
    const int* lst = buckets + b * R_;

    for (int i = tid; i < n; i += 256) {
        int r = lst[i];
        const float* bx = box + (size_t)r * 5;

        // ---- R10-frozen edge arithmetic ----
        float x1 = rintf(bx[1]);
        float y1 = rintf(bx[2]);
        float x2 = rintf(bx[3] + 1.0f);
        float y2 = rintf(bx[4] + 1.0f);

        float roi_w = fmaxf(x2 - x1, 0.1f);
        float roi_h = fmaxf(y2 - y1, 0.1f);

        const float RCP7 = __uint_as_float(0x3E124925u); // fl32(1/7)
        float bin_w = roi_w * RCP7;
        float bin_h = roi_h * RCP7;
        asm volatile("" : "+v"(bin_w), "+v"(bin_h));

        float hs_f = floorf(sep_ma((float)ph,       bin_h, y1));
        float he_f = ceilf (sep_ma((float)(ph + 1), bin_h, y1));
        float ws_f = floorf(sep_ma((float)pw,       bin_w, x1));
        float we_f = ceilf (sep_ma((float)(pw + 1), bin_w, x1));

        int hs = (int)fminf(fmaxf(hs_f, 0.0f), 80.0f);
        int he = (int)fminf(fmaxf(he_f, 0.0f), 80.0f);
        int ws = (int)fminf(fmaxf(ws_f, 0.0f), 80.0f);
        int we = (int)fminf(fmaxf(we_f, 0.0f), 80.0f);

        float s11 = S[he * SATW + we];
        float s01 = S[hs * SATW + we];
        float s10 = S[he * SATW + ws];
        float s00 = S[hs * SATW + ws];
        float bin_sum = ((s11 - s01) - s10) + s00;

        int area = (he - hs) * (we - ws);
        out[(size_t)r * C_ + c] = (area > 0) ? bin_sum / (float)area : 0.0f;
    }
}

// ---- fallback: R11 direct-sum kernel (ws too small) ----
__global__ __launch_bounds__(256) void psroi_direct_kernel(
    const float* __restrict__ fsam,
    const float* __restrict__ box,
    float* __restrict__ out)
{
    int id = blockIdx.x;
    int j  = id & 7;
    int m  = id >> 3;
    int g  = (m < 512) ? j : j + 8;
    int l  = (m < 512) ? m : m - 512;
    int c    = g * 16 + (l >> 5);
    int rblk = l & 31;
    if (c >= C_) return;

    int r = rblk * 256 + (int)threadIdx.x;
    int pw = c % P_;
    int ph = (c / P_) % P_;

    const float* bx = box + (size_t)r * 5;
    int   b  = (int)bx[0];
    float x1 = rintf(bx[1]);
    float y1 = rintf(bx[2]);
    float x2 = rintf(bx[3] + 1.0f);
    float y2 = rintf(bx[4] + 1.0f);

    float roi_w = fmaxf(x2 - x1, 0.1f);
    float roi_h = fmaxf(y2 - y1, 0.1f);

    const float RCP7 = __uint_as_float(0x3E124925u);
    float bin_w = roi_w * RCP7;
    float bin_h = roi_h * RCP7;
    asm volatile("" : "+v"(bin_w), "+v"(bin_h));

    float hs_f = floorf(sep_ma((float)ph,       bin_h, y1));
    float he_f = ceilf (sep_ma((float)(ph + 1), bin_h, y1));
    float ws_f = floorf(sep_ma((float)pw,       bin_w, x1));
    float we_f = ceilf (sep_ma((float)(pw + 1), bin_w, x1));

    int hs = (int)fminf(fmaxf(hs_f, 0.0f), 80.0f);
    int he = (int)fminf(fmaxf(he_f, 0.0f), 80.0f);
    int ws = (int)fminf(fmaxf(ws_f, 0.0f), 80.0f);
    int we = (int)fminf(fmaxf(we_f, 0.0f), 80.0f);

    const float* plane = fsam + ((size_t)b * C_ + c) * (H_ * W_);
    float s = 0.0f;
    for (int y = hs; y < he; ++y) {
        const float* row = plane + y * W_;
        for (int x = ws; x < we; ++x) s += row[x];
    }
    int area = (he - hs) * (we - ws);
    out[(size_t)r * C_ + c] = (area > 0) ? s / (float)area : 0.0f;
}

extern "C" void kernel_launch(void* const* d_in, const int* in_sizes, int n_in,
                              void* d_out, int out_size, void* d_ws, size_t ws_size,
                              hipStream_t stream) {
    const float* fsam = (const float*)d_in[0];
    const float* box  = (const float*)d_in[1];
    float* out = (float*)d_out;

    // ws layout: [0,32) counts (8 ints), [32, 32+8*8192*4) buckets
    size_t need = 32 + (size_t)N_ * R_ * sizeof(int);   // 262176 B
    if (ws_size >= need) {
        int* cnt     = (int*)d_ws;
        int* buckets = (int*)((char*)d_ws + 32);
        bucket_kernel<<<N_, 256, 0, stream>>>(box, cnt, buckets);
        fused_kernel<<<N_ * C_, 256, 0, stream>>>(fsam, box, cnt, buckets, out);
    } else {
        psroi_direct_kernel<<<8192, 256, 0, stream>>>(fsam, box, out);
    }
}

// Round 15
// 39.271 us; speedup vs baseline: 2.0512x; 1.1481x over previous
//
#include <hip/hip_runtime.h>

// PSROI pooling: fsam (N=8, C=245, H=80, W=80) f32, box (R=8192, 5) f32
// out (R, 245) f32. out[r, c] = mean over fsam[b, c, hs:he, ws:we].
//
// ARITHMETIC (frozen since R10, DO NOT TOUCH): bin = roi * fl32(1/7)
// (reciprocal multiply, 0x3E124925) and edges = SEPARATELY-rounded
// g*bin + off (asm barriers). Matches ref (absmax <= 0.016 << 0.0725).
//
// R15: vectorized LDS life-cycle. R13/R14's SAT used an 81-stride +1-offset
// layout -> every LDS touch was b32 (49k ds-ops/block ~ 4.6k LDS-pipe
// cycles; x7.66 blocks/CU ~ 15us/CU serialization). Now S[80][84] (rows
// 16B-aligned, no pad row/col): float4 loads -> ds_write_b128; both scans
// read/write 10x b128 per thread and scan IN REGISTERS with the chunk
// offset folded into the writeback (no second RMW pass). SAT boundary
// (hs==0/ws==0) handled by clamp+select in the pool's 4 taps.

#define N_ 8
#define C_ 245
#define H_ 80
#define W_ 80
#define R_ 8192
#define P_ 7
#define SROW 84                    // row stride in floats (21 float4)

// XLA-style separately-rounded a*b + c in f32; barriers forbid contraction.
__device__ __forceinline__ float sep_ma(float a, float b, float c) {
    float p = a * b;                 // v_mul_f32, IEEE RN
    asm volatile("" : "+v"(p));      // contraction barrier
    float s = p + c;                 // v_add_f32, IEEE RN
    asm volatile("" : "+v"(s));
    return s;
}

// ---- kernel 1: deterministic bucket build (8 blocks, no atomics) ----
__global__ __launch_bounds__(256) void bucket_kernel(
    const float* __restrict__ box, int* __restrict__ cnt,
    int* __restrict__ buckets)
{
    __shared__ int psum[256];
    int b = blockIdx.x;                    // image
    int t = threadIdx.x;
    int r0 = t * 32;                       // contiguous range per thread

    unsigned pack[4] = {0u, 0u, 0u, 0u};   // 32 b-values as nibbles
    int m = 0;
    #pragma unroll
    for (int k = 0; k < 32; ++k) {
        int bb = (int)box[(size_t)(r0 + k) * 5];
        pack[k >> 3] |= (unsigned)bb << ((k & 7) * 4);
        m += (bb == b);
    }
    psum[t] = m;
    __syncthreads();

    // Hillis-Steele inclusive scan over 256 counts
    for (int off = 1; off < 256; off <<= 1) {
        int v = (t >= off) ? psum[t - off] : 0;
        __syncthreads();
        psum[t] += v;
        __syncthreads();
    }
    int pos = psum[t] - m;                 // exclusive prefix
    #pragma unroll
    for (int k = 0; k < 32; ++k) {
        int bb = (int)((pack[k >> 3] >> ((k & 7) * 4)) & 15u);
        if (bb == b) buckets[b * R_ + pos++] = r0 + k;
    }
    if (t == 255) cnt[b] = psum[255];
}

__device__ __forceinline__ float4 f4_add(float4 a, float4 b) {
    return make_float4(a.x + b.x, a.y + b.y, a.z + b.z, a.w + b.w);
}

// ---- kernel 2: fused SAT-in-LDS + pool, all-b128 LDS traffic ----
__global__ __launch_bounds__(256) void fused_kernel(
    const float* __restrict__ fsam,
    const float* __restrict__ box,
    const int* __restrict__ cnt,
    const int* __restrict__ buckets,
    float* __restrict__ out)
{
    __shared__ float S[H_ * SROW];         // 26880 B, rows 16B-aligned
    int id  = blockIdx.x;                  // 0..1959
    int b   = id & 7;                      // image (XCD swizzle: XCD = b)
    int c   = id >> 3;                     // channel 0..244
    int tid = threadIdx.x;

    const float* plane = fsam + ((size_t)b * C_ + c) * (H_ * W_);

    // ---- load: 1600 float4, coalesced global -> b128 LDS ----
    for (int i = tid; i < 1600; i += 256) {
        int row = (int)((unsigned)i / 20u);
        int c4  = i - row * 20;
        float4 v = ((const float4*)plane)[i];        // word 4i = row*80+c4*4
        ((float4*)S)[row * 21 + c4] = v;
    }
    __syncthreads();

    // ---- horizontal scan: 80 rows x 2 halves of 40, in registers ----
    if (tid < 160) {
        int row = tid >> 1, half = tid & 1;
        float4* base = (float4*)S + row * 21 + half * 10;
        float v[40];
        #pragma unroll
        for (int q = 0; q < 10; ++q) {
            float4 t = base[q];
            v[4*q+0] = t.x; v[4*q+1] = t.y; v[4*q+2] = t.z; v[4*q+3] = t.w;
        }
        float run = 0.0f;
        #pragma unroll
        for (int j = 0; j < 40; ++j) { run += v[j]; v[j] = run; }
        float other = __shfl_xor(run, 1);            // partner half's total
        if (half) {
            #pragma unroll
            for (int j = 0; j < 40; ++j) v[j] += other;
        }
        #pragma unroll
        for (int q = 0; q < 10; ++q)
            base[q] = make_float4(v[4*q+0], v[4*q+1], v[4*q+2], v[4*q+3]);
    }
    __syncthreads();

    // ---- vertical scan: 20 col-groups x 8 chunks of 10 rows, float4 regs --
    if (tid < 160) {
        int cg = tid >> 3;                 // 0..19 (cols cg*4..cg*4+3)
        int ch = tid & 7;                  // 0..7  (rows ch*10..ch*10+9)
        float4* col = (float4*)S + cg;
        float4 v[10];
        float4 run = make_float4(0.f, 0.f, 0.f, 0.f);
        #pragma unroll
        for (int j = 0; j < 10; ++j) {
            run = f4_add(run, col[(ch * 10 + j) * 21]);
            v[j] = run;
        }
        // exclusive scan of chunk totals across the 8 chunk lanes (same wave)
        float4 incl = run;
        #pragma unroll
        for (int d = 1; d < 8; d <<= 1) {
            float4 u;
            u.x = __shfl_up(incl.x, d, 8);
            u.y = __shfl_up(incl.y, d, 8);
            u.z = __shfl_up(incl.z, d, 8);
            u.w = __shfl_up(incl.w, d, 8);
            if ((tid & 7) >= d) incl = f4_add(incl, u);
        }
        float4 off = make_float4(incl.x - run.x, incl.y - run.y,
                                 incl.z - run.z, incl.w - run.w);
        #pragma unroll
        for (int j = 0; j < 10; ++j)
            col[(ch * 10 + j) * 21] = f4_add(v[j], off);
    }
    __syncthreads();

    // ---- pool this image's ROIs from the LDS SAT ----
    int ph = (c / P_) % P_;                // block-uniform
    int pw = c % P_;
    int n  = cnt[b];
    const int* lst = buckets + b * R_;

    for (int i = tid; i < n; i += 256) {
        int r = lst[i];
        const float* bx = box + (size_t)r * 5;

        // ---- R10-frozen edge arithmetic ----
        float x1 = rintf(bx[1]);
        float y1 = rintf(bx[2]);
        float x2 = rintf(bx[3] + 1.0f);
        float y2 = rintf(bx[4] + 1.0f);

        float roi_w = fmaxf(x2 - x1, 0.1f);
        float roi_h = fmaxf(y2 - y1, 0.1f);

        const float RCP7 = __uint_as_float(0x3E124925u); // fl32(1/7)
        float bin_w = roi_w * RCP7;
        float bin_h = roi_h * RCP7;
        asm volatile("" : "+v"(bin_w), "+v"(bin_h));

        float hs_f = floorf(sep_ma((float)ph,       bin_h, y1));
        float he_f = ceilf (sep_ma((float)(ph + 1), bin_h, y1));
        float ws_f = floorf(sep_ma((float)pw,       bin_w, x1));
        float we_f = ceilf (sep_ma((float)(pw + 1), bin_w, x1));

        int hs = (int)fminf(fmaxf(hs_f, 0.0f), 80.0f);
        int he = (int)fminf(fmaxf(he_f, 0.0f), 80.0f);
        int ws = (int)fminf(fmaxf(ws_f, 0.0f), 80.0f);
        int we = (int)fminf(fmaxf(we_f, 0.0f), 80.0f);

        // SAT taps with implicit zero row/col: T(i,j) = S[i-1][j-1],
        // 0 if i==0 or j==0 (clamped read + select, non-divergent)
        float t11, t01, t10, t00;
        {
            int i1 = he > 0 ? he - 1 : 0, i0 = hs > 0 ? hs - 1 : 0;
            int j1 = we > 0 ? we - 1 : 0, j0 = ws > 0 ? ws - 1 : 0;
            float v11 = S[i1 * SROW + j1];
            float v01 = S[i0 * SROW + j1];
            float v10 = S[i1 * SROW + j0];
            float v00 = S[i0 * SROW + j0];
            t11 = (he > 0 && we > 0) ? v11 : 0.0f;
            t01 = (hs > 0 && we > 0) ? v01 : 0.0f;
            t10 = (he > 0 && ws > 0) ? v10 : 0.0f;
            t00 = (hs > 0 && ws > 0) ? v00 : 0.0f;
        }
        float bin_sum = ((t11 - t01) - t10) + t00;   // ref op order

        int area = (he - hs) * (we - ws);
        out[(size_t)r * C_ + c] = (area > 0) ? bin_sum / (float)area : 0.0f;
    }
}

// ---- fallback: R11 direct-sum kernel (ws too small) ----
__global__ __launch_bounds__(256) void psroi_direct_kernel(
    const float* __restrict__ fsam,
    const float* __restrict__ box,
    float* __restrict__ out)
{
    int id = blockIdx.x;
    int j  = id & 7;
    int m  = id >> 3;
    int g  = (m < 512) ? j : j + 8;
    int l  = (m < 512) ? m : m - 512;
    int c    = g * 16 + (l >> 5);
    int rblk = l & 31;
    if (c >= C_) return;

    int r = rblk * 256 + (int)threadIdx.x;
    int pw = c % P_;
    int ph = (c / P_) % P_;

    const float* bx = box + (size_t)r * 5;
    int   b  = (int)bx[0];
    float x1 = rintf(bx[1]);
    float y1 = rintf(bx[2]);
    float x2 = rintf(bx[3] + 1.0f);
    float y2 = rintf(bx[4] + 1.0f);

    float roi_w = fmaxf(x2 - x1, 0.1f);
    float roi_h = fmaxf(y2 - y1, 0.1f);

    const float RCP7 = __uint_as_float(0x3E124925u);
    float bin_w = roi_w * RCP7;
    float bin_h = roi_h * RCP7;
    asm volatile("" : "+v"(bin_w), "+v"(bin_h));

    float hs_f = floorf(sep_ma((float)ph,       bin_h, y1));
    float he_f = ceilf (sep_ma((float)(ph + 1), bin_h, y1));
    float ws_f = floorf(sep_ma((float)pw,       bin_w, x1));
    float we_f = ceilf (sep_ma((float)(pw + 1), bin_w, x1));

    int hs = (int)fminf(fmaxf(hs_f, 0.0f), 80.0f);
    int he = (int)fminf(fmaxf(he_f, 0.0f), 80.0f);
    int ws = (int)fminf(fmaxf(ws_f, 0.0f), 80.0f);
    int we = (int)fminf(fmaxf(we_f, 0.0f), 80.0f);

    const float* plane = fsam + ((size_t)b * C_ + c) * (H_ * W_);
    float s = 0.0f;
    for (int y = hs; y < he; ++y) {
        const float* row = plane + y * W_;
        for (int x = ws; x < we; ++x) s += row[x];
    }
    int area = (he - hs) * (we - ws);
    out[(size_t)r * C_ + c] = (area > 0) ? s / (float)area : 0.0f;
}

extern "C" void kernel_launch(void* const* d_in, const int* in_sizes, int n_in,
                              void* d_out, int out_size, void* d_ws, size_t ws_size,
                              hipStream_t stream) {
    const float* fsam = (const float*)d_in[0];
    const float* box  = (const float*)d_in[1];
    float* out = (float*)d_out;

    // ws layout: [0,32) counts (8 ints), [32, 32+8*8192*4) buckets
    size_t need = 32 + (size_t)N_ * R_ * sizeof(int);   // 262176 B
    if (ws_size >= need) {
        int* cnt     = (int*)d_ws;
        int* buckets = (int*)((char*)d_ws + 32);
        bucket_kernel<<<N_, 256, 0, stream>>>(box, cnt, buckets);
        fused_kernel<<<N_ * C_, 256, 0, stream>>>(fsam, box, cnt, buckets, out);
    } else {
        psroi_direct_kernel<<<8192, 256, 0, stream>>>(fsam, box, out);
    }
}